// Round 14
// baseline (152.344 us; speedup 1.0000x reference)
//
#include <hip/hip_runtime.h>

#define DEV __device__ __forceinline__

typedef int v4i __attribute__((ext_vector_type(4)));
typedef short v8s __attribute__((ext_vector_type(8)));
typedef float v4f __attribute__((ext_vector_type(4)));
typedef unsigned long long u64;

// quantize pre-scaled y3 = 3*y: clamp to [0,3], round-to-even
DEV unsigned int quant3(float y3) {
    return (unsigned int)(int)rintf(fminf(fmaxf(y3, 0.f), 3.f));
}

DEV int imax(int a, int b) { return a > b ? a : b; }
DEV int imin(int a, int b) { return a < b ? a : b; }

// float -> bf16 bits, round-to-nearest-even (x never NaN here)
DEV unsigned int f2bf(float x) {
    union { float f; unsigned u; } v; v.f = x;
    unsigned r = v.u + 0x7fffu + ((v.u >> 16) & 1u);
    return r >> 16;
}
DEV float bf2f(unsigned int b) {
    union { unsigned u; float f; } v; v.u = b << 16;
    return v.f;
}
#define SPLIT3(v, H, M, L)                        \
    unsigned int H = f2bf(v);                     \
    float r1_##H = (v) - bf2f(H);                 \
    unsigned int M = f2bf(r1_##H);                \
    unsigned int L = f2bf(r1_##H - bf2f(M));

DEV v8s mk_v8s(u64 a, u64 b) {
    union { u64 q[2]; v8s s; } u; u.q[0] = a; u.q[1] = b; return u.s;
}

// channel-permutation: channel c stored at byte pos(c) within each 64B pixel
// vector (so a lane's 4 nt-bytes pack into one dword: pos(nt*16+lr)=lr*4+nt).
DEV int chpos(int c) { return (c & 15) * 4 + (c >> 4); }

// ---------------------------------------------------------------------------
// conv1 via bf16 MFMA, full-K (R10 engine) + FOLDED k_signs tail
// (i = b*256+tid covers all 1,048,576 >= 819,200 sign elements; conv2 runs
// only after conv1 completes, so w2p/w3p/fw1s are ready).
// ---------------------------------------------------------------------------
__global__ __launch_bounds__(256, 8) void k_conv1_mfma(
    const float* __restrict__ x, const float* __restrict__ w1f,
    const float* __restrict__ b1, unsigned char* __restrict__ a1,
    const float* __restrict__ w2, const float* __restrict__ w3,
    const float* __restrict__ fw1,
    char* __restrict__ w2p, char* __restrict__ w3p, char* __restrict__ fw1s) {
    __shared__ u64 simg[960];     // [30][32] split records
    __shared__ float sxf[960];    // [30][32] fp32 padded image
    int b = blockIdx.x, tid = threadIdx.x;
    for (int i = tid; i < 960; i += 256) {
        int y = i >> 5, xc = i & 31;
        float v = 0.f;
        if (y >= 1 && y <= 28 && xc >= 1 && xc <= 28)
            v = x[(size_t)b * 784 + (y - 1) * 28 + (xc - 1)];
        sxf[i] = v;
        SPLIT3(v, h, m, lo);
        simg[i] = (u64)(h | (m << 16)) | ((u64)lo << 32);
    }
    int l = tid & 63, lr = l & 15, lg = l >> 4, w = tid >> 6;
    int t0 = lg * 2, t1 = t0 + 1;
    int ky0 = (t0 * 21846) >> 16, kx0 = t0 - ky0 * 3;
    int ky1 = (t1 * 21846) >> 16, kx1 = t1 - ky1 * 3;
    int dt0 = (ky0 * 32 + kx0) * 8, dt1 = (ky1 * 32 + kx1) * 8;
    v8s bf[4];
    float s8[4], b3[4];
#pragma unroll
    for (int nt = 0; nt < 4; ++nt) {
        const float* wr = w1f + (nt * 16 + lr) * 9;
        unsigned sa = (wr[t0] >= 0.f) ? 0x3F80u : 0xBF80u;
        unsigned sb = (wr[t1] >= 0.f) ? 0x3F80u : 0xBF80u;
        union { unsigned d[4]; v8s s; } u;
        u.d[0] = sa | (sa << 16); u.d[1] = sa;
        u.d[2] = sb | (sb << 16); u.d[3] = sb;
        bf[nt] = u.s;
        s8[nt] = (wr[8] >= 0.f) ? 1.f : -1.f;
        b3[nt] = 3.f * b1[nt * 16 + lr];
    }
    __syncthreads();

    const unsigned char* sib = (const unsigned char*)simg;
    unsigned char* outb = a1 + (size_t)b * 12544;
    for (int mt = w; mt < 49; mt += 4) {
        int s = mt * 4 + (lr >> 2);
        int qy = (s * 4682) >> 16;            // /14
        int qx = s - qy * 14;
        int cy = 2 * qy + ((lr >> 1) & 1);
        int cx = 2 * qx + (lr & 1);
        int base = (cy * 32 + cx) * 8;
        u64 qa = *(const u64*)(sib + base + dt0);
        u64 qb = *(const u64*)(sib + base + dt1);
        v8s af = mk_v8s(qa, qb);
        v4f a0 = {0.f, 0.f, 0.f, 0.f}, a1v = {0.f, 0.f, 0.f, 0.f};
        v4f a2v = {0.f, 0.f, 0.f, 0.f}, a3v = {0.f, 0.f, 0.f, 0.f};
        a0  = __builtin_amdgcn_mfma_f32_16x16x32_bf16(af, bf[0], a0, 0, 0, 0);
        a1v = __builtin_amdgcn_mfma_f32_16x16x32_bf16(af, bf[1], a1v, 0, 0, 0);
        a2v = __builtin_amdgcn_mfma_f32_16x16x32_bf16(af, bf[2], a2v, 0, 0, 0);
        a3v = __builtin_amdgcn_mfma_f32_16x16x32_bf16(af, bf[3], a3v, 0, 0, 0);
        int q = mt * 4 + lg;
        int Qy = (q * 4682) >> 16;
        int Qx = q - Qy * 14;
        const float* xr = &sxf[(2 * Qy + 2) * 32 + (2 * Qx + 2)];
        float x8_0 = xr[0], x8_1 = xr[1], x8_2 = xr[32], x8_3 = xr[33];
        unsigned dw;
        {
            float m0 = fmaxf(fmaxf(fmaf(s8[0], x8_0, a0[0]),  fmaf(s8[0], x8_1, a0[1])),
                             fmaxf(fmaf(s8[0], x8_2, a0[2]),  fmaf(s8[0], x8_3, a0[3])));
            float m1 = fmaxf(fmaxf(fmaf(s8[1], x8_0, a1v[0]), fmaf(s8[1], x8_1, a1v[1])),
                             fmaxf(fmaf(s8[1], x8_2, a1v[2]), fmaf(s8[1], x8_3, a1v[3])));
            float m2 = fmaxf(fmaxf(fmaf(s8[2], x8_0, a2v[0]), fmaf(s8[2], x8_1, a2v[1])),
                             fmaxf(fmaf(s8[2], x8_2, a2v[2]), fmaf(s8[2], x8_3, a2v[3])));
            float m3 = fmaxf(fmaxf(fmaf(s8[3], x8_0, a3v[0]), fmaf(s8[3], x8_1, a3v[1])),
                             fmaxf(fmaf(s8[3], x8_2, a3v[2]), fmaf(s8[3], x8_3, a3v[3])));
            dw  = quant3(fmaf(m0, 3.f, b3[0]));
            dw |= quant3(fmaf(m1, 3.f, b3[1])) << 8;
            dw |= quant3(fmaf(m2, 3.f, b3[2])) << 16;
            dw |= quant3(fmaf(m3, 3.f, b3[3])) << 24;
        }
        *(unsigned*)(outb + q * 64 + lr * 4) = dw;
    }

    // ---- folded k_signs tail (independent global work)
    {
        int i = b * 256 + tid;
        if (i < 36864) {
            int co = i / 576, r = i - co * 576;
            int ci = r / 9, t = r - ci * 9;
            int p = chpos(ci);
            int off = t * 4096 + (p >> 4) * 1024 + co * 16 + (p & 15);
            w2p[off] = (w2[i] >= 0.f) ? 1 : -1;
            w3p[off] = (w3[i] >= 0.f) ? 1 : -1;
        }
        if (i < 819200) {
            int o = i / 1600, r2 = i - o * 1600;
            int pix = r2 >> 6, ch = r2 & 63;
            fw1s[o * 1600 + pix * 64 + chpos(ch)] = (fw1[i] >= 0.f) ? 1 : -1;
        }
    }
}

// ---------------------------------------------------------------------------
// conv2 via i8 MFMA, 512 threads, 2 images/block. v4: weights read DIRECTLY
// from global w2p (L2-resident 36KB broadcast) -> no sw stage, LDS 32.8 KB
// -> 3 blocks/CU (24 waves, +50% vs R12's 16). Engine otherwise unchanged.
// ---------------------------------------------------------------------------
__global__ __launch_bounds__(512, 6) void k_conv2_mfma(
    const unsigned char* __restrict__ a1, const char* __restrict__ w2p,
    const float* __restrict__ g1, const float* __restrict__ be1,
    const float* __restrict__ m1, const float* __restrict__ v1,
    unsigned char* __restrict__ a2) {
    __shared__ unsigned char sa[2 * 16384];  // [img][ck][16x16 pad pix][16]
    int b0 = blockIdx.x * 2, tid = threadIdx.x;
    if (tid < 480) {
        int imz = (tid >= 240) ? 1 : 0;
        int t2 = tid - imz * 240;
        int ck = t2 & 3, e = t2 >> 2;
        int py, px;
        if (e < 16)      { py = 0;      px = e; }
        else if (e < 32) { py = 15;     px = e - 16; }
        else if (e < 46) { py = e - 31; px = 0; }
        else             { py = e - 45; px = 15; }
        *(uint4*)(sa + imz * 16384 + ck * 4096 + (py * 16 + px) * 16) =
            make_uint4(0, 0, 0, 0);
    }
    {
        const uint4* src = (const uint4*)(a1 + (size_t)b0 * 12544);
        for (int i = tid; i < 1568; i += 512) {
            int im = i / 784, r = i - im * 784;
            int ck = r / 196, pixel = r - ck * 196;
            int py = pixel / 14, px = pixel - py * 14;
            *(uint4*)(sa + im * 16384 + ck * 4096 + ((py + 1) * 16 + px + 1) * 16) =
                src[im * 784 + pixel * 4 + ck];
        }
    }
    __syncthreads();

    int w8 = tid >> 6, l = tid & 63;
    int img = w8 >> 2, w = w8 & 3;
    int lr = l & 15, lg = l >> 4;
    const unsigned char* sai = sa + img * 16384;
    int abase[4], mts[4];
#pragma unroll
    for (int j = 0; j < 4; ++j) {
        int mt = w + 4 * j;
        mts[j] = mt;
        int s = mt * 4 + (lr >> 2);
        if (s > 48) s = 48;
        int qy = s / 7, qx = s - qy * 7;
        int ty = 2 * qy + ((lr >> 1) & 1);
        int tx = 2 * qx + (lr & 1);
        abase[j] = lg * 4096 + (ty * 16 + tx) * 16;
    }
    v4i acc[4][4] = {};
    const char* wbase = w2p + lg * 1024 + lr * 16;
#pragma unroll
    for (int t = 0; t < 9; ++t) {
        int ky = t / 3, kx = t - ky * 3;
        v4i bfw[4];
#pragma unroll
        for (int nt = 0; nt < 4; ++nt)
            bfw[nt] = *(const v4i*)(wbase + t * 4096 + nt * 256);
        int aoff = (ky * 16 + kx) * 16;
#pragma unroll
        for (int j = 0; j < 4; ++j) {
            if (mts[j] < 13) {
                v4i af = *(const v4i*)(sai + abase[j] + aoff);
#pragma unroll
                for (int nt = 0; nt < 4; ++nt)
                    acc[j][nt] = __builtin_amdgcn_mfma_i32_16x16x64_i8(
                        af, bfw[nt], acc[j][nt], 0, 0, 0);
            }
        }
    }

    float sc4[4], of4[4];
#pragma unroll
    for (int nt = 0; nt < 4; ++nt) {
        int ch = nt * 16 + lr;
        float si = g1[ch] * rsqrtf(v1[ch] + 1e-4f);
        sc4[nt] = si;
        of4[nt] = 3.f * (be1[ch] - m1[ch] * si);
    }
#pragma unroll
    for (int j = 0; j < 4; ++j) {
        int q = mts[j] * 4 + lg;
        if (q < 49) {
            unsigned dw = 0;
#pragma unroll
            for (int nt = 0; nt < 4; ++nt) {
                int mx = imax(imax(acc[j][nt][0], acc[j][nt][1]),
                              imax(acc[j][nt][2], acc[j][nt][3]));
                int mn = imin(imin(acc[j][nt][0], acc[j][nt][1]),
                              imin(acc[j][nt][2], acc[j][nt][3]));
                float sc = sc4[nt];
                int v = (sc >= 0.f) ? mx : mn;
                dw |= quant3(fmaf((float)v, sc, of4[nt])) << (8 * nt);
            }
            *(unsigned*)(a2 + (size_t)(b0 + img) * 3136 + q * 64 + lr * 4) = dw;
        }
    }
}

// ---------------------------------------------------------------------------
// conv3 via i8 MFMA: 4 images/block. v3: weights direct from global w3p,
// LDS 22.8 KB -> 6 blocks/CU.
// ---------------------------------------------------------------------------
__global__ __launch_bounds__(256, 6) void k_conv3_mfma(
    const unsigned char* __restrict__ a2, const char* __restrict__ w3p,
    const float* __restrict__ g2, const float* __restrict__ be2,
    const float* __restrict__ m2, const float* __restrict__ v2,
    unsigned char* __restrict__ a3) {
    __shared__ unsigned char sa[4 * 3136];   // [img][ck][49][16]
    __shared__ unsigned char so[4 * 2560];   // [img][32 pix][80]
    int b0 = blockIdx.x * 4, tid = threadIdx.x;
    {
        const uint4* src = (const uint4*)(a2 + (size_t)b0 * 3136);
        for (int i = tid; i < 784; i += 256) {
            int img = i / 196, r = i - img * 196;
            int ck = r / 49, pixel = r - ck * 49;
            *(uint4*)(sa + img * 3136 + ck * 784 + pixel * 16) =
                src[img * 196 + pixel * 4 + ck];
        }
    }
    __syncthreads();

    int w = tid >> 6, l = tid & 63;
    int lr = l & 15, lg = l >> 4;
    const unsigned char* sai = sa + w * 3136;
    int abase[2];
#pragma unroll
    for (int mt = 0; mt < 2; ++mt) {
        int p = mt * 16 + lr;
        if (p > 24) p = 24;
        int oy = p / 5, ox = p - oy * 5;
        abase[mt] = lg * 784 + (oy * 7 + ox) * 16;
    }
    v4i acc[2][4] = {};
    const char* wbase = w3p + lg * 1024 + lr * 16;
#pragma unroll
    for (int t = 0; t < 9; ++t) {
        int ky = t / 3, kx = t - ky * 3;
        v4i bfw[4];
#pragma unroll
        for (int nt = 0; nt < 4; ++nt)
            bfw[nt] = *(const v4i*)(wbase + t * 4096 + nt * 256);
        int aoff = (ky * 7 + kx) * 16;
#pragma unroll
        for (int mt = 0; mt < 2; ++mt) {
            v4i af = *(const v4i*)(sai + abase[mt] + aoff);
#pragma unroll
            for (int nt = 0; nt < 4; ++nt)
                acc[mt][nt] = __builtin_amdgcn_mfma_i32_16x16x64_i8(
                    af, bfw[nt], acc[mt][nt], 0, 0, 0);
        }
    }

    float sc4[4], of4[4];
#pragma unroll
    for (int nt = 0; nt < 4; ++nt) {
        int ch = nt * 16 + lr;
        float si = g2[ch] * rsqrtf(v2[ch] + 1e-4f);
        sc4[nt] = si;
        of4[nt] = 3.f * (be2[ch] - m2[ch] * si);
    }
    unsigned char* soi = so + w * 2560;
#pragma unroll
    for (int mt = 0; mt < 2; ++mt)
#pragma unroll
        for (int r = 0; r < 4; ++r) {
            int pixel = mt * 16 + lg * 4 + r;
            unsigned dw = 0;
#pragma unroll
            for (int nt = 0; nt < 4; ++nt)
                dw |= quant3(fmaf((float)acc[mt][nt][r], sc4[nt], of4[nt])) << (8 * nt);
            *(unsigned*)(soi + pixel * 80 + lr * 4) = dw;
        }
    __syncthreads();
    for (int idx = tid; idx < 400; idx += 256) {
        int img = idx / 100, r = idx - img * 100;
        int p = r >> 2, c0 = r & 3;
        *(uint4*)(a3 + (size_t)(b0 + img) * 1600 + r * 16) =
            *(const uint4*)(so + img * 2560 + p * 80 + c0 * 16);
    }
}

// ---------------------------------------------------------------------------
// fc1 via i8 MFMA, 64M x 32N tiles (R13 structure), (256,8) -> 8 blocks/CU.
// ---------------------------------------------------------------------------
__global__ __launch_bounds__(256, 8) void k_fc1_mfma(
    const unsigned char* __restrict__ a3, const char* __restrict__ fw1s,
    const float* __restrict__ fb1, float* __restrict__ h1) {
    __shared__ unsigned char sA[64 * 80];
    __shared__ unsigned char sB[32 * 80];
    __shared__ float sbias[32];
    int bb = (blockIdx.x >> 4) * 64;
    int ob = (blockIdx.x & 15) * 32;
    int tid = threadIdx.x;
    int row = tid >> 2, seg = tid & 3;
    if (tid < 32) sbias[tid] = fb1[ob + tid];
    const unsigned char* Ag = a3 + (size_t)(bb + row) * 1600 + seg * 16;
    const char* Bg = fw1s + (size_t)(ob + (row & 31)) * 1600 + seg * 16;
    uint4 av = *(const uint4*)Ag;
    uint4 bv = make_uint4(0, 0, 0, 0);
    if (tid < 128) bv = *(const uint4*)Bg;

    int w = tid >> 6, l = tid & 63;
    int wm = w >> 1, wn = w & 1;
    int lr = l & 15, lg = l >> 4;
    const unsigned char* sAr = sA + (wm * 32 + lr) * 80 + lg * 16;
    const unsigned char* sBr = sB + (wn * 16 + lr) * 80 + lg * 16;
    v4i acc[2] = {};

    for (int k0 = 0; k0 < 1600; k0 += 64) {
        *(uint4*)(sA + row * 80 + seg * 16) = av;
        if (tid < 128) *(uint4*)(sB + row * 80 + seg * 16) = bv;
        __syncthreads();
        if (k0 < 1536) {
            av = *(const uint4*)(Ag + k0 + 64);
            if (tid < 128) bv = *(const uint4*)(Bg + k0 + 64);
        }
        v4i af0 = *(const v4i*)(sAr);
        v4i af1 = *(const v4i*)(sAr + 16 * 80);
        v4i bf0 = *(const v4i*)(sBr);
        acc[0] = __builtin_amdgcn_mfma_i32_16x16x64_i8(af0, bf0, acc[0], 0, 0, 0);
        acc[1] = __builtin_amdgcn_mfma_i32_16x16x64_i8(af1, bf0, acc[1], 0, 0, 0);
        __syncthreads();
    }

    const float inv3 = 1.f / 3.f;
    int gcol = ob + wn * 16 + lr;
    float bias = sbias[wn * 16 + lr];
#pragma unroll
    for (int mt = 0; mt < 2; ++mt)
#pragma unroll
        for (int r = 0; r < 4; ++r) {
            int grow = bb + wm * 32 + mt * 16 + lg * 4 + r;
            h1[(size_t)grow * 512 + gcol] = (float)acc[mt][r] * inv3 + bias;
        }
}

// ---------------------------------------------------------------------------
// fc2 + log_softmax (unchanged)
// ---------------------------------------------------------------------------
__global__ __launch_bounds__(256) void k_fc2(
    const float* __restrict__ h1, const float* __restrict__ fw2,
    const float* __restrict__ fb2, float* __restrict__ out) {
    __shared__ float sw[5120];
    __shared__ float sb[16];
    int tid = threadIdx.x;
    for (int i = tid; i < 5120; i += 256) sw[i] = fw2[i];
    if (tid < 10) sb[tid] = fb2[tid];
    __syncthreads();

    int wv = tid >> 6, lane = tid & 63;
    int b = blockIdx.x * 4 + wv;
    const float* hr = h1 + (size_t)b * 512;
    float p[10];
#pragma unroll
    for (int o = 0; o < 10; ++o) p[o] = 0.f;
    for (int k = lane; k < 512; k += 64) {
        float hv = hr[k];
#pragma unroll
        for (int o = 0; o < 10; ++o) p[o] += hv * sw[o * 512 + k];
    }
#pragma unroll
    for (int o = 0; o < 10; ++o) {
#pragma unroll
        for (int off = 32; off > 0; off >>= 1) p[o] += __shfl_xor(p[o], off, 64);
        p[o] += sb[o];
    }
    float mx = p[0];
#pragma unroll
    for (int o = 1; o < 10; ++o) mx = fmaxf(mx, p[o]);
    float se = 0.f;
#pragma unroll
    for (int o = 0; o < 10; ++o) se += expf(p[o] - mx);
    float lse = logf(se) + mx;
    float myv = 0.f;
#pragma unroll
    for (int o = 0; o < 10; ++o) myv = (lane == o) ? p[o] : myv;
    if (lane < 10) out[(size_t)b * 10 + lane] = myv - lse;
}

// ---------------------------------------------------------------------------
extern "C" void kernel_launch(void* const* d_in, const int* in_sizes, int n_in,
                              void* d_out, int out_size, void* d_ws, size_t ws_size,
                              hipStream_t stream) {
    const float* x   = (const float*)d_in[0];
    const float* w1  = (const float*)d_in[1];
    const float* b1  = (const float*)d_in[2];
    const float* w2  = (const float*)d_in[3];
    const float* g1  = (const float*)d_in[4];
    const float* be1 = (const float*)d_in[5];
    const float* m1  = (const float*)d_in[6];
    const float* v1  = (const float*)d_in[7];
    const float* w3  = (const float*)d_in[8];
    const float* g2  = (const float*)d_in[9];
    const float* be2 = (const float*)d_in[10];
    const float* m2  = (const float*)d_in[11];
    const float* v2  = (const float*)d_in[12];
    const float* fw1 = (const float*)d_in[13];
    const float* fb1 = (const float*)d_in[14];
    const float* fw2 = (const float*)d_in[15];
    const float* fb2 = (const float*)d_in[16];
    float* out = (float*)d_out;

    char* ws = (char*)d_ws;
    char* w2p  = ws;                                   // 36864
    char* w3p  = ws + 36864;                           // 36864
    char* fw1s = ws + 73728;                           // 819200
    unsigned char* a1 = (unsigned char*)(ws + 892928); // 4096*12544 = 51380224
    unsigned char* a2 = a1 + 51380224;                 // 4096*3136  = 12845056
    unsigned char* a3 = a2 + 12845056;                 // 4096*1600  = 6553600
    float* h1 = (float*)(void*)a1;                     // alias: a1 dead when fc1 runs

    k_conv1_mfma<<<4096, 256, 0, stream>>>(x, w1, b1, a1, w2, w3, fw1,
                                           w2p, w3p, fw1s);
    k_conv2_mfma<<<2048, 512, 0, stream>>>(a1, w2p, g1, be1, m1, v1, a2);
    k_conv3_mfma<<<1024, 256, 0, stream>>>(a2, w3p, g2, be2, m2, v2, a3);
    k_fc1_mfma<<<1024, 256, 0, stream>>>(a3, fw1s, fb1, h1);
    k_fc2<<<1024, 256, 0, stream>>>(h1, fw2, fb2, out);
}

// Round 15
// 99.208 us; speedup vs baseline: 1.5356x; 1.5356x over previous
//
#include <hip/hip_runtime.h>

#define DEV __device__ __forceinline__

typedef int v4i __attribute__((ext_vector_type(4)));
typedef short v8s __attribute__((ext_vector_type(8)));
typedef float v4f __attribute__((ext_vector_type(4)));
typedef unsigned long long u64;

// quantize pre-scaled y3 = 3*y: clamp to [0,3], round-to-even
DEV unsigned int quant3(float y3) {
    return (unsigned int)(int)rintf(fminf(fmaxf(y3, 0.f), 3.f));
}

DEV int imax(int a, int b) { return a > b ? a : b; }
DEV int imin(int a, int b) { return a < b ? a : b; }

// float -> bf16 bits, round-to-nearest-even (x never NaN here)
DEV unsigned int f2bf(float x) {
    union { float f; unsigned u; } v; v.f = x;
    unsigned r = v.u + 0x7fffu + ((v.u >> 16) & 1u);
    return r >> 16;
}
DEV float bf2f(unsigned int b) {
    union { unsigned u; float f; } v; v.u = b << 16;
    return v.f;
}
#define SPLIT3(v, H, M, L)                        \
    unsigned int H = f2bf(v);                     \
    float r1_##H = (v) - bf2f(H);                 \
    unsigned int M = f2bf(r1_##H);                \
    unsigned int L = f2bf(r1_##H - bf2f(M));

DEV v8s mk_v8s(u64 a, u64 b) {
    union { u64 q[2]; v8s s; } u; u.q[0] = a; u.q[1] = b; return u.s;
}

// channel-permutation: channel c stored at byte pos(c) within each 64B pixel
// vector (so a lane's 4 nt-bytes pack into one dword: pos(nt*16+lr)=lr*4+nt).
DEV int chpos(int c) { return (c & 15) * 4 + (c >> 4); }

// ---------------------------------------------------------------------------
// conv1 via bf16 MFMA, full-K (R10 engine) + FOLDED k_signs tail (R14 piece
// that worked): i = b*256+tid covers all 1,048,576 >= 819,200 sign elements;
// conv2/conv3/fc1 launch after conv1, so w2p/w3p/fw1s are ready in-stream.
// ---------------------------------------------------------------------------
__global__ __launch_bounds__(256, 8) void k_conv1_mfma(
    const float* __restrict__ x, const float* __restrict__ w1f,
    const float* __restrict__ b1, unsigned char* __restrict__ a1,
    const float* __restrict__ w2, const float* __restrict__ w3,
    const float* __restrict__ fw1,
    char* __restrict__ w2p, char* __restrict__ w3p, char* __restrict__ fw1s) {
    __shared__ u64 simg[960];     // [30][32] split records
    __shared__ float sxf[960];    // [30][32] fp32 padded image
    int b = blockIdx.x, tid = threadIdx.x;
    for (int i = tid; i < 960; i += 256) {
        int y = i >> 5, xc = i & 31;
        float v = 0.f;
        if (y >= 1 && y <= 28 && xc >= 1 && xc <= 28)
            v = x[(size_t)b * 784 + (y - 1) * 28 + (xc - 1)];
        sxf[i] = v;
        SPLIT3(v, h, m, lo);
        simg[i] = (u64)(h | (m << 16)) | ((u64)lo << 32);
    }
    int l = tid & 63, lr = l & 15, lg = l >> 4, w = tid >> 6;
    int t0 = lg * 2, t1 = t0 + 1;
    int ky0 = (t0 * 21846) >> 16, kx0 = t0 - ky0 * 3;
    int ky1 = (t1 * 21846) >> 16, kx1 = t1 - ky1 * 3;
    int dt0 = (ky0 * 32 + kx0) * 8, dt1 = (ky1 * 32 + kx1) * 8;
    v8s bf[4];
    float s8[4], b3[4];
#pragma unroll
    for (int nt = 0; nt < 4; ++nt) {
        const float* wr = w1f + (nt * 16 + lr) * 9;
        unsigned sa = (wr[t0] >= 0.f) ? 0x3F80u : 0xBF80u;
        unsigned sb = (wr[t1] >= 0.f) ? 0x3F80u : 0xBF80u;
        union { unsigned d[4]; v8s s; } u;
        u.d[0] = sa | (sa << 16); u.d[1] = sa;
        u.d[2] = sb | (sb << 16); u.d[3] = sb;
        bf[nt] = u.s;
        s8[nt] = (wr[8] >= 0.f) ? 1.f : -1.f;
        b3[nt] = 3.f * b1[nt * 16 + lr];
    }
    __syncthreads();

    const unsigned char* sib = (const unsigned char*)simg;
    unsigned char* outb = a1 + (size_t)b * 12544;
    for (int mt = w; mt < 49; mt += 4) {
        int s = mt * 4 + (lr >> 2);
        int qy = (s * 4682) >> 16;            // /14
        int qx = s - qy * 14;
        int cy = 2 * qy + ((lr >> 1) & 1);
        int cx = 2 * qx + (lr & 1);
        int base = (cy * 32 + cx) * 8;
        u64 qa = *(const u64*)(sib + base + dt0);
        u64 qb = *(const u64*)(sib + base + dt1);
        v8s af = mk_v8s(qa, qb);
        v4f a0 = {0.f, 0.f, 0.f, 0.f}, a1v = {0.f, 0.f, 0.f, 0.f};
        v4f a2v = {0.f, 0.f, 0.f, 0.f}, a3v = {0.f, 0.f, 0.f, 0.f};
        a0  = __builtin_amdgcn_mfma_f32_16x16x32_bf16(af, bf[0], a0, 0, 0, 0);
        a1v = __builtin_amdgcn_mfma_f32_16x16x32_bf16(af, bf[1], a1v, 0, 0, 0);
        a2v = __builtin_amdgcn_mfma_f32_16x16x32_bf16(af, bf[2], a2v, 0, 0, 0);
        a3v = __builtin_amdgcn_mfma_f32_16x16x32_bf16(af, bf[3], a3v, 0, 0, 0);
        int q = mt * 4 + lg;
        int Qy = (q * 4682) >> 16;
        int Qx = q - Qy * 14;
        const float* xr = &sxf[(2 * Qy + 2) * 32 + (2 * Qx + 2)];
        float x8_0 = xr[0], x8_1 = xr[1], x8_2 = xr[32], x8_3 = xr[33];
        unsigned dw;
        {
            float m0 = fmaxf(fmaxf(fmaf(s8[0], x8_0, a0[0]),  fmaf(s8[0], x8_1, a0[1])),
                             fmaxf(fmaf(s8[0], x8_2, a0[2]),  fmaf(s8[0], x8_3, a0[3])));
            float m1 = fmaxf(fmaxf(fmaf(s8[1], x8_0, a1v[0]), fmaf(s8[1], x8_1, a1v[1])),
                             fmaxf(fmaf(s8[1], x8_2, a1v[2]), fmaf(s8[1], x8_3, a1v[3])));
            float m2 = fmaxf(fmaxf(fmaf(s8[2], x8_0, a2v[0]), fmaf(s8[2], x8_1, a2v[1])),
                             fmaxf(fmaf(s8[2], x8_2, a2v[2]), fmaf(s8[2], x8_3, a2v[3])));
            float m3 = fmaxf(fmaxf(fmaf(s8[3], x8_0, a3v[0]), fmaf(s8[3], x8_1, a3v[1])),
                             fmaxf(fmaf(s8[3], x8_2, a3v[2]), fmaf(s8[3], x8_3, a3v[3])));
            dw  = quant3(fmaf(m0, 3.f, b3[0]));
            dw |= quant3(fmaf(m1, 3.f, b3[1])) << 8;
            dw |= quant3(fmaf(m2, 3.f, b3[2])) << 16;
            dw |= quant3(fmaf(m3, 3.f, b3[3])) << 24;
        }
        *(unsigned*)(outb + q * 64 + lr * 4) = dw;
    }

    // ---- folded k_signs tail (independent global work)
    {
        int i = b * 256 + tid;
        if (i < 36864) {
            int co = i / 576, r = i - co * 576;
            int ci = r / 9, t = r - ci * 9;
            int p = chpos(ci);
            int off = t * 4096 + (p >> 4) * 1024 + co * 16 + (p & 15);
            w2p[off] = (w2[i] >= 0.f) ? 1 : -1;
            w3p[off] = (w3[i] >= 0.f) ? 1 : -1;
        }
        if (i < 819200) {
            int o = i / 1600, r2 = i - o * 1600;
            int pix = r2 >> 6, ch = r2 & 63;
            fw1s[o * 1600 + pix * 64 + chpos(ch)] = (fw1[i] >= 0.f) ? 1 : -1;
        }
    }
}

// ---------------------------------------------------------------------------
// conv2 via i8 MFMA, 512 threads, 2 images/block, LDS weight stage
// (R12 proven version — REVERTED from R14's global-weights regression).
// ---------------------------------------------------------------------------
__global__ __launch_bounds__(512, 4) void k_conv2_mfma(
    const unsigned char* __restrict__ a1, const char* __restrict__ w2p,
    const float* __restrict__ g1, const float* __restrict__ be1,
    const float* __restrict__ m1, const float* __restrict__ v1,
    unsigned char* __restrict__ a2) {
    __shared__ unsigned char sa[2 * 16384];  // [img][ck][16x16 pad pix][16]
    __shared__ char sw[36864];               // [t][ck][64 co][16]
    int b0 = blockIdx.x * 2, tid = threadIdx.x;
    if (tid < 480) {
        int imz = (tid >= 240) ? 1 : 0;
        int t2 = tid - imz * 240;
        int ck = t2 & 3, e = t2 >> 2;
        int py, px;
        if (e < 16)      { py = 0;      px = e; }
        else if (e < 32) { py = 15;     px = e - 16; }
        else if (e < 46) { py = e - 31; px = 0; }
        else             { py = e - 45; px = 15; }
        *(uint4*)(sa + imz * 16384 + ck * 4096 + (py * 16 + px) * 16) =
            make_uint4(0, 0, 0, 0);
    }
    {
        const uint4* src = (const uint4*)(a1 + (size_t)b0 * 12544);
        for (int i = tid; i < 1568; i += 512) {
            int im = i / 784, r = i - im * 784;
            int ck = r / 196, pixel = r - ck * 196;
            int py = pixel / 14, px = pixel - py * 14;
            *(uint4*)(sa + im * 16384 + ck * 4096 + ((py + 1) * 16 + px + 1) * 16) =
                src[im * 784 + pixel * 4 + ck];
        }
        const uint4* wsrc = (const uint4*)w2p;
        uint4* wdst = (uint4*)sw;
        for (int i = tid; i < 2304; i += 512) wdst[i] = wsrc[i];
    }
    __syncthreads();

    int w8 = tid >> 6, l = tid & 63;
    int img = w8 >> 2, w = w8 & 3;
    int lr = l & 15, lg = l >> 4;
    const unsigned char* sai = sa + img * 16384;
    int abase[4], mts[4];
#pragma unroll
    for (int j = 0; j < 4; ++j) {
        int mt = w + 4 * j;
        mts[j] = mt;
        int s = mt * 4 + (lr >> 2);
        if (s > 48) s = 48;
        int qy = s / 7, qx = s - qy * 7;
        int ty = 2 * qy + ((lr >> 1) & 1);
        int tx = 2 * qx + (lr & 1);
        abase[j] = lg * 4096 + (ty * 16 + tx) * 16;
    }
    v4i acc[4][4] = {};
#pragma unroll
    for (int t = 0; t < 9; ++t) {
        int ky = t / 3, kx = t - ky * 3;
        int boff = t * 4096 + lg * 1024 + lr * 16;
        v4i bfw[4];
#pragma unroll
        for (int nt = 0; nt < 4; ++nt)
            bfw[nt] = *(const v4i*)(sw + boff + nt * 256);
        int aoff = (ky * 16 + kx) * 16;
#pragma unroll
        for (int j = 0; j < 4; ++j) {
            if (mts[j] < 13) {
                v4i af = *(const v4i*)(sai + abase[j] + aoff);
#pragma unroll
                for (int nt = 0; nt < 4; ++nt)
                    acc[j][nt] = __builtin_amdgcn_mfma_i32_16x16x64_i8(
                        af, bfw[nt], acc[j][nt], 0, 0, 0);
            }
        }
    }

    float sc4[4], of4[4];
#pragma unroll
    for (int nt = 0; nt < 4; ++nt) {
        int ch = nt * 16 + lr;
        float si = g1[ch] * rsqrtf(v1[ch] + 1e-4f);
        sc4[nt] = si;
        of4[nt] = 3.f * (be1[ch] - m1[ch] * si);
    }
#pragma unroll
    for (int j = 0; j < 4; ++j) {
        int q = mts[j] * 4 + lg;
        if (q < 49) {
            unsigned dw = 0;
#pragma unroll
            for (int nt = 0; nt < 4; ++nt) {
                int mx = imax(imax(acc[j][nt][0], acc[j][nt][1]),
                              imax(acc[j][nt][2], acc[j][nt][3]));
                int mn = imin(imin(acc[j][nt][0], acc[j][nt][1]),
                              imin(acc[j][nt][2], acc[j][nt][3]));
                float sc = sc4[nt];
                int v = (sc >= 0.f) ? mx : mn;
                dw |= quant3(fmaf((float)v, sc, of4[nt])) << (8 * nt);
            }
            *(unsigned*)(a2 + (size_t)(b0 + img) * 3136 + q * 64 + lr * 4) = dw;
        }
    }
}

// ---------------------------------------------------------------------------
// conv3 via i8 MFMA: 4 images/block, LDS weight stage (R10 proven version —
// REVERTED from R14's global-weights regression).
// ---------------------------------------------------------------------------
__global__ __launch_bounds__(256, 2) void k_conv3_mfma(
    const unsigned char* __restrict__ a2, const char* __restrict__ w3p,
    const float* __restrict__ g2, const float* __restrict__ be2,
    const float* __restrict__ m2, const float* __restrict__ v2,
    unsigned char* __restrict__ a3) {
    __shared__ unsigned char sa[4 * 3136];   // [img][ck][49][16]
    __shared__ char sw[36864];               // [t][ck][64 co][16]
    __shared__ unsigned char so[4 * 2560];   // [img][32 pix][80]
    int b0 = blockIdx.x * 4, tid = threadIdx.x;
    {
        const uint4* src = (const uint4*)(a2 + (size_t)b0 * 3136);
        for (int i = tid; i < 784; i += 256) {
            int img = i / 196, r = i - img * 196;
            int ck = r / 49, pixel = r - ck * 49;
            *(uint4*)(sa + img * 3136 + ck * 784 + pixel * 16) =
                src[img * 196 + pixel * 4 + ck];
        }
        const uint4* wsrc = (const uint4*)w3p;
        uint4* wdst = (uint4*)sw;
        for (int i = tid; i < 2304; i += 256) wdst[i] = wsrc[i];
    }
    __syncthreads();

    int w = tid >> 6, l = tid & 63;
    int lr = l & 15, lg = l >> 4;
    const unsigned char* sai = sa + w * 3136;
    int abase[2];
#pragma unroll
    for (int mt = 0; mt < 2; ++mt) {
        int p = mt * 16 + lr;
        if (p > 24) p = 24;
        int oy = p / 5, ox = p - oy * 5;
        abase[mt] = lg * 784 + (oy * 7 + ox) * 16;
    }
    v4i acc[2][4] = {};
#pragma unroll
    for (int t = 0; t < 9; ++t) {
        int ky = t / 3, kx = t - ky * 3;
        int boff = t * 4096 + lg * 1024 + lr * 16;
        v4i bfw[4];
#pragma unroll
        for (int nt = 0; nt < 4; ++nt)
            bfw[nt] = *(const v4i*)(sw + boff + nt * 256);
        int aoff = (ky * 7 + kx) * 16;
#pragma unroll
        for (int mt = 0; mt < 2; ++mt) {
            v4i af = *(const v4i*)(sai + abase[mt] + aoff);
#pragma unroll
            for (int nt = 0; nt < 4; ++nt)
                acc[mt][nt] = __builtin_amdgcn_mfma_i32_16x16x64_i8(
                    af, bfw[nt], acc[mt][nt], 0, 0, 0);
        }
    }

    float sc4[4], of4[4];
#pragma unroll
    for (int nt = 0; nt < 4; ++nt) {
        int ch = nt * 16 + lr;
        float si = g2[ch] * rsqrtf(v2[ch] + 1e-4f);
        sc4[nt] = si;
        of4[nt] = 3.f * (be2[ch] - m2[ch] * si);
    }
    unsigned char* soi = so + w * 2560;
#pragma unroll
    for (int mt = 0; mt < 2; ++mt)
#pragma unroll
        for (int r = 0; r < 4; ++r) {
            int pixel = mt * 16 + lg * 4 + r;
            unsigned dw = 0;
#pragma unroll
            for (int nt = 0; nt < 4; ++nt)
                dw |= quant3(fmaf((float)acc[mt][nt][r], sc4[nt], of4[nt])) << (8 * nt);
            *(unsigned*)(soi + pixel * 80 + lr * 4) = dw;
        }
    __syncthreads();
    for (int idx = tid; idx < 400; idx += 256) {
        int img = idx / 100, r = idx - img * 100;
        int p = r >> 2, c0 = r & 3;
        *(uint4*)(a3 + (size_t)(b0 + img) * 1600 + r * 16) =
            *(const uint4*)(so + img * 2560 + p * 80 + c0 * 16);
    }
}

// ---------------------------------------------------------------------------
// fc1 via i8 MFMA, 64M x 32N tiles (R13 structure, neutral-kept).
// ---------------------------------------------------------------------------
__global__ __launch_bounds__(256, 8) void k_fc1_mfma(
    const unsigned char* __restrict__ a3, const char* __restrict__ fw1s,
    const float* __restrict__ fb1, float* __restrict__ h1) {
    __shared__ unsigned char sA[64 * 80];
    __shared__ unsigned char sB[32 * 80];
    __shared__ float sbias[32];
    int bb = (blockIdx.x >> 4) * 64;
    int ob = (blockIdx.x & 15) * 32;
    int tid = threadIdx.x;
    int row = tid >> 2, seg = tid & 3;
    if (tid < 32) sbias[tid] = fb1[ob + tid];
    const unsigned char* Ag = a3 + (size_t)(bb + row) * 1600 + seg * 16;
    const char* Bg = fw1s + (size_t)(ob + (row & 31)) * 1600 + seg * 16;
    uint4 av = *(const uint4*)Ag;
    uint4 bv = make_uint4(0, 0, 0, 0);
    if (tid < 128) bv = *(const uint4*)Bg;

    int w = tid >> 6, l = tid & 63;
    int wm = w >> 1, wn = w & 1;
    int lr = l & 15, lg = l >> 4;
    const unsigned char* sAr = sA + (wm * 32 + lr) * 80 + lg * 16;
    const unsigned char* sBr = sB + (wn * 16 + lr) * 80 + lg * 16;
    v4i acc[2] = {};

    for (int k0 = 0; k0 < 1600; k0 += 64) {
        *(uint4*)(sA + row * 80 + seg * 16) = av;
        if (tid < 128) *(uint4*)(sB + row * 80 + seg * 16) = bv;
        __syncthreads();
        if (k0 < 1536) {
            av = *(const uint4*)(Ag + k0 + 64);
            if (tid < 128) bv = *(const uint4*)(Bg + k0 + 64);
        }
        v4i af0 = *(const v4i*)(sAr);
        v4i af1 = *(const v4i*)(sAr + 16 * 80);
        v4i bf0 = *(const v4i*)(sBr);
        acc[0] = __builtin_amdgcn_mfma_i32_16x16x64_i8(af0, bf0, acc[0], 0, 0, 0);
        acc[1] = __builtin_amdgcn_mfma_i32_16x16x64_i8(af1, bf0, acc[1], 0, 0, 0);
        __syncthreads();
    }

    const float inv3 = 1.f / 3.f;
    int gcol = ob + wn * 16 + lr;
    float bias = sbias[wn * 16 + lr];
#pragma unroll
    for (int mt = 0; mt < 2; ++mt)
#pragma unroll
        for (int r = 0; r < 4; ++r) {
            int grow = bb + wm * 32 + mt * 16 + lg * 4 + r;
            h1[(size_t)grow * 512 + gcol] = (float)acc[mt][r] * inv3 + bias;
        }
}

// ---------------------------------------------------------------------------
// fc2 + log_softmax (unchanged)
// ---------------------------------------------------------------------------
__global__ __launch_bounds__(256) void k_fc2(
    const float* __restrict__ h1, const float* __restrict__ fw2,
    const float* __restrict__ fb2, float* __restrict__ out) {
    __shared__ float sw[5120];
    __shared__ float sb[16];
    int tid = threadIdx.x;
    for (int i = tid; i < 5120; i += 256) sw[i] = fw2[i];
    if (tid < 10) sb[tid] = fb2[tid];
    __syncthreads();

    int wv = tid >> 6, lane = tid & 63;
    int b = blockIdx.x * 4 + wv;
    const float* hr = h1 + (size_t)b * 512;
    float p[10];
#pragma unroll
    for (int o = 0; o < 10; ++o) p[o] = 0.f;
    for (int k = lane; k < 512; k += 64) {
        float hv = hr[k];
#pragma unroll
        for (int o = 0; o < 10; ++o) p[o] += hv * sw[o * 512 + k];
    }
#pragma unroll
    for (int o = 0; o < 10; ++o) {
#pragma unroll
        for (int off = 32; off > 0; off >>= 1) p[o] += __shfl_xor(p[o], off, 64);
        p[o] += sb[o];
    }
    float mx = p[0];
#pragma unroll
    for (int o = 1; o < 10; ++o) mx = fmaxf(mx, p[o]);
    float se = 0.f;
#pragma unroll
    for (int o = 0; o < 10; ++o) se += expf(p[o] - mx);
    float lse = logf(se) + mx;
    float myv = 0.f;
#pragma unroll
    for (int o = 0; o < 10; ++o) myv = (lane == o) ? p[o] : myv;
    if (lane < 10) out[(size_t)b * 10 + lane] = myv - lse;
}

// ---------------------------------------------------------------------------
extern "C" void kernel_launch(void* const* d_in, const int* in_sizes, int n_in,
                              void* d_out, int out_size, void* d_ws, size_t ws_size,
                              hipStream_t stream) {
    const float* x   = (const float*)d_in[0];
    const float* w1  = (const float*)d_in[1];
    const float* b1  = (const float*)d_in[2];
    const float* w2  = (const float*)d_in[3];
    const float* g1  = (const float*)d_in[4];
    const float* be1 = (const float*)d_in[5];
    const float* m1  = (const float*)d_in[6];
    const float* v1  = (const float*)d_in[7];
    const float* w3  = (const float*)d_in[8];
    const float* g2  = (const float*)d_in[9];
    const float* be2 = (const float*)d_in[10];
    const float* m2  = (const float*)d_in[11];
    const float* v2  = (const float*)d_in[12];
    const float* fw1 = (const float*)d_in[13];
    const float* fb1 = (const float*)d_in[14];
    const float* fw2 = (const float*)d_in[15];
    const float* fb2 = (const float*)d_in[16];
    float* out = (float*)d_out;

    char* ws = (char*)d_ws;
    char* w2p  = ws;                                   // 36864
    char* w3p  = ws + 36864;                           // 36864
    char* fw1s = ws + 73728;                           // 819200
    unsigned char* a1 = (unsigned char*)(ws + 892928); // 4096*12544 = 51380224
    unsigned char* a2 = a1 + 51380224;                 // 4096*3136  = 12845056
    unsigned char* a3 = a2 + 12845056;                 // 4096*1600  = 6553600
    float* h1 = (float*)(void*)a1;                     // alias: a1 dead when fc1 runs

    k_conv1_mfma<<<4096, 256, 0, stream>>>(x, w1, b1, a1, w2, w3, fw1,
                                           w2p, w3p, fw1s);
    k_conv2_mfma<<<2048, 512, 0, stream>>>(a1, w2p, g1, be1, m1, v1, a2);
    k_conv3_mfma<<<1024, 256, 0, stream>>>(a2, w3p, g2, be2, m2, v2, a3);
    k_fc1_mfma<<<1024, 256, 0, stream>>>(a3, fw1s, fb1, h1);
    k_fc2<<<1024, 256, 0, stream>>>(h1, fw2, fb2, out);
}